// Round 6
// baseline (252.395 us; speedup 1.0000x reference)
//
#include <hip/hip_runtime.h>
#include <hip/hip_bf16.h>

#define NE    16
#define KDIM  1024
#define NDIM  1024
#define BATCH 8192
#define TM    128
#define TN    64
#define MAXT  96          // max live m-tiles = 64 + 15 = 79, padded

typedef __attribute__((ext_vector_type(8))) short short8;
typedef __attribute__((ext_vector_type(4))) float floatx4;
typedef unsigned short ushort_t;

// ---- ws layout (bytes) ----
#define O_TG0  1024
#define O_TE   2048
#define O_TEND 3072
#define O_GIDX 4096                     // int[8192]
#define O_TOK  36864                    // int[8320]
#define O_PA   73728                    // ushort[(8192+128)*1024]
#define WS_REQ 17113088

__device__ __forceinline__ unsigned int pk2bf(float x, float y) {
    __hip_bfloat162 h = __float22bfloat162_rn(make_float2(x, y));
    unsigned int u;
    __builtin_memcpy(&u, &h, 4);
    return u;
}

// ---------------- fast path ----------------

// Single-block map: ballot-based ranking (no LDS atomics). Emits gidx
// (token -> sorted slot) + tile map at TM granularity.
__global__ __launch_bounds__(1024) void map_k(
        const int* __restrict__ gate, int* __restrict__ gidx,
        int* __restrict__ tg0, int* __restrict__ te, int* __restrict__ tend) {
    __shared__ int ccnt[128][NE];    // per-chunk per-expert counts (8 KB)
    __shared__ int cbase[128][NE];   // per-chunk exclusive base     (8 KB)
    __shared__ int ebase[NE];
    __shared__ int etot[NE];
    const int tid = threadIdx.x;
    const int wv = tid >> 6, ln = tid & 63;

    ((int*)ccnt)[tid] = 0;
    ((int*)ccnt)[tid + 1024] = 0;
    __syncthreads();

    int e[8], rk[8];
    #pragma unroll
    for (int i = 0; i < 8; ++i) {
        const int chunk = wv * 8 + i;
        const int t = chunk * 64 + ln;
        const int ei = gate[t];
        unsigned long long m = ~0ull;
        #pragma unroll
        for (int b = 0; b < 4; ++b) {
            unsigned long long bb = __ballot(((ei >> b) & 1) != 0);
            m &= ((ei >> b) & 1) ? bb : ~bb;
        }
        const unsigned int lo = (unsigned int)m;
        const unsigned int hi = (unsigned int)(m >> 32);
        const int r = __builtin_amdgcn_mbcnt_hi(
            hi, __builtin_amdgcn_mbcnt_lo(lo, 0));
        if (r == 0) ccnt[chunk][ei] = __popcll(m);
        e[i] = ei; rk[i] = r;
    }
    __syncthreads();

    if (tid < NE) {                   // 16-thread scan over 128 chunks
        int s = 0;
        for (int c = 0; c < 128; ++c) { cbase[c][tid] = s; s += ccnt[c][tid]; }
        etot[tid] = s;
    }
    __syncthreads();

    if (tid == 0) {                   // expert bases + tile map (tiny)
        int o = 0, nt = 0;
        for (int j = 0; j < NE; ++j) {
            ebase[j] = o;
            int c = etot[j];
            for (int rr = 0; rr < c; rr += TM) {
                int r0 = (rr + TM <= c) ? rr : (c > TM ? c - TM : 0);
                tg0[nt] = o + r0; te[nt] = j; tend[nt] = o + c; ++nt;
            }
            o += c;
        }
        for (; nt < MAXT; ++nt) { tg0[nt] = 0; te[nt] = 0; tend[nt] = 0; }
    }
    __syncthreads();

    #pragma unroll
    for (int i = 0; i < 8; ++i) {
        const int chunk = wv * 8 + i;
        const int t = chunk * 64 + ln;
        gidx[t] = ebase[e[i]] + cbase[chunk][e[i]] + rk[i];
    }
}

// token gather: fp32 -> bf16, destination row from gidx (no scans)
__global__ __launch_bounds__(256, 8) void gather_k(
        const float* __restrict__ inp, const int* __restrict__ gidx,
        ushort_t* __restrict__ pA, int* __restrict__ tok) {
    const int b = blockIdx.x, tid = threadIdx.x;
    const int col = (tid & 127) * 8;
    const int half = tid >> 7;
    int g[2]; float4 v0[2], v1[2];
    #pragma unroll
    for (int p = 0; p < 2; ++p) {
        int t = b * 4 + p * 2 + half;
        g[p] = gidx[t];
        v0[p] = *(const float4*)&inp[(size_t)t * KDIM + col];
        v1[p] = *(const float4*)&inp[(size_t)t * KDIM + col + 4];
    }
    #pragma unroll
    for (int p = 0; p < 2; ++p) {
        uint4 u = make_uint4(pk2bf(v0[p].x, v0[p].y), pk2bf(v0[p].z, v0[p].w),
                             pk2bf(v1[p].x, v1[p].y), pk2bf(v1[p].z, v1[p].w));
        *(uint4*)&pA[(size_t)g[p] * KDIM + col] = u;
        if (col == 0) tok[g[p]] = b * 4 + p * 2 + half;
    }
}

// TM=128 x TN=64, BK=64, T14 async-STAGE split (round-6):
// per iter: ds_write staged regs -> __syncthreads (vmem already drained at
// reg-use, so its vmcnt(0) is a no-op) -> ISSUE k+1 global loads -> MFMA ->
// raw lgkm-barrier (prefetch loads survive it). The R2 structure exposed the
// full staging latency at every stage-sync (8 VMEM issued then vmcnt(0)
// drained ~700cyc with ~200cyc compute -> 12% MfmaUtil, 62us).
// NOTE (r1): A-dbuf via +16KB LDS regressed (residency). This holds LDS at
// 25KB and double-buffers in REGISTERS instead.
// NOTE (r3): XCD m-tile swizzle regressed (weights dominate fetch; default
// x-fastest order pins column-panel c to XCD c%8 -> weight slice L2-resident).
// NOTE (r4): fp32 direct A-gather regressed (FETCH +60MB). Keep bf16 pA.
// NOTE (r5): occupancy 56% at TMG=64 was SLOWER -> not TLP-bound; don't
// shrink tiles for residency.
__global__ __launch_bounds__(256, 4) void moe_gemm8_k(
        const ushort_t* __restrict__ pA, const float* __restrict__ wgt,
        const int* __restrict__ tg0, const int* __restrict__ teArr,
        const int* __restrict__ tend, const int* __restrict__ tok,
        float* __restrict__ out) {
    const int y   = blockIdx.y;
    const int g0  = tg0[y];
    const int end = tend[y];
    if (g0 >= end) return;
    const int e    = teArr[y];
    const int out0 = blockIdx.x * TN;

    __shared__ ushort_t As[TM][64];   // 16 KB, chunk-swizzled content
    __shared__ ushort_t Bs[TN][64];   //  8 KB
    __shared__ int tok_s[TM];

    const int tid = threadIdx.x;
    if (tid < TM) tok_s[tid] = tok[g0 + tid];

    const int wave = tid >> 6, lane = tid & 63;
    const int wm = (wave >> 1) * 64;
    const int wn = (wave & 1) * 32;
    const int quad = lane >> 4, l16 = lane & 15;
    const int c8 = tid & 7;           // chunk 0..7 (16B granule)
    const int rb = tid >> 3;          // 0..31

    const ushort_t* Ab = pA + (size_t)g0 * KDIM;
    const float*    Bw = wgt + ((size_t)e * NDIM + out0) * KDIM;

    // per-thread source pointers, chunk pre-swizzled per row so LDS content
    // matches the XOR-swizzled read side: As[row][c] = A[row][c ^ (row&7)]
    const ushort_t* asrc[4];
    #pragma unroll
    for (int i = 0; i < 4; ++i) {
        int row = rb + 32 * i;
        asrc[i] = Ab + (size_t)row * KDIM + (c8 ^ (row & 7)) * 8;
    }
    const float* bsrc[2];
    #pragma unroll
    for (int i = 0; i < 2; ++i) {
        int slot = i * 256 + tid;
        int row = slot >> 3;
        bsrc[i] = Bw + (size_t)row * KDIM + ((slot & 7) ^ (row & 7)) * 8;
    }

    floatx4 acc[4][2] = {};
    uint4  av[4];
    float4 bv[2][2];

    // prologue: prefetch tile k0=0 into registers
    #pragma unroll
    for (int i = 0; i < 4; ++i) av[i] = *(const uint4*)(asrc[i]);
    #pragma unroll
    for (int i = 0; i < 2; ++i) {
        bv[i][0] = *(const float4*)(bsrc[i]);
        bv[i][1] = *(const float4*)(bsrc[i] + 4);
    }

    for (int k0 = 0; k0 < KDIM; k0 += 64) {
        // write staged regs to LDS (linear dest, conflict-free b128)
        #pragma unroll
        for (int i = 0; i < 4; ++i)
            *(uint4*)&As[rb + 32 * i][c8 * 8] = av[i];
        #pragma unroll
        for (int i = 0; i < 2; ++i) {
            int slot = i * 256 + tid;
            uint4 u = make_uint4(pk2bf(bv[i][0].x, bv[i][0].y),
                                 pk2bf(bv[i][0].z, bv[i][0].w),
                                 pk2bf(bv[i][1].x, bv[i][1].y),
                                 pk2bf(bv[i][1].z, bv[i][1].w));
            *(uint4*)((ushort_t*)Bs + (size_t)slot * 8) = u;
        }
        __syncthreads();              // vmem already retired; orders LDS writes

        // issue NEXT tile's global loads; they fly across MFMA + barrier and
        // are waited on only at next iter's ds_write use
        if (k0 + 64 < KDIM) {
            #pragma unroll
            for (int i = 0; i < 4; ++i)
                av[i] = *(const uint4*)(asrc[i] + k0 + 64);
            #pragma unroll
            for (int i = 0; i < 2; ++i) {
                bv[i][0] = *(const float4*)(bsrc[i] + k0 + 64);
                bv[i][1] = *(const float4*)(bsrc[i] + k0 + 68);
            }
        }

        #pragma unroll
        for (int s = 0; s < 2; ++s) {
            short8 a[4], b[2];
            #pragma unroll
            for (int i = 0; i < 4; ++i) {
                int r = wm + i * 16 + l16;
                a[i] = *(const short8*)&As[r][((s * 4 + quad) ^ (r & 7)) * 8];
            }
            #pragma unroll
            for (int j = 0; j < 2; ++j) {
                int r = wn + j * 16 + l16;
                b[j] = *(const short8*)&Bs[r][((s * 4 + quad) ^ (r & 7)) * 8];
            }
            #pragma unroll
            for (int mi = 0; mi < 4; ++mi)
                #pragma unroll
                for (int nj = 0; nj < 2; ++nj)
                    acc[mi][nj] = __builtin_amdgcn_mfma_f32_16x16x32_bf16(
                        a[mi], b[nj], acc[mi][nj], 0, 0, 0);
        }
        // end-of-step barrier WITHOUT vmcnt drain: LDS reads done, then sync;
        // the register prefetch stays in flight (this is the whole point)
        asm volatile("s_waitcnt lgkmcnt(0)" ::: "memory");
        __builtin_amdgcn_s_barrier();
    }

    // C/D layout: col=lane&15, row=quad*4+reg (verified m89/m91)
    #pragma unroll
    for (int mi = 0; mi < 4; ++mi) {
        #pragma unroll
        for (int r = 0; r < 4; ++r) {
            int lrow = wm + mi * 16 + quad * 4 + r;
            if (g0 + lrow < end) {
                int t = tok_s[lrow];
                float* orow = out + (size_t)t * NDIM + out0 + wn + l16;
                #pragma unroll
                for (int nj = 0; nj < 2; ++nj)
                    orow[nj * 16] = acc[mi][nj][r];
            }
        }
    }
}

// ---------------- fallback path (round-1, known-passing) ----------------
#define LDW 20
__global__ void zero_k(int* cnt) {
    if (threadIdx.x < NE) cnt[threadIdx.x] = 0;
}

__global__ void bin_tokens_k(const int* __restrict__ gate, int* cnt, int* idx) {
    int t = blockIdx.x * blockDim.x + threadIdx.x;
    if (t < BATCH) {
        int e = gate[t];
        int p = atomicAdd(&cnt[e], 1);
        idx[e * BATCH + p] = t;
    }
}

__global__ __launch_bounds__(256) void moe_gemm_k(
        const float* __restrict__ inp, const float* __restrict__ wgt,
        const int* __restrict__ cnt, const int* __restrict__ idx,
        float* __restrict__ out) {
    const int e = blockIdx.z;
    const int n_e = cnt[e];
    const int row0 = blockIdx.y * TM;
    if (row0 >= n_e) return;
    const int out0 = blockIdx.x * 128;
    __shared__ unsigned int As[TM * LDW];
    __shared__ unsigned int Bs[TM * LDW];
    __shared__ int tok_s[TM];
    const int tid = threadIdx.x;
    if (tid < TM) {
        int g = row0 + tid;
        tok_s[tid] = (g < n_e) ? idx[e * BATCH + g] : -1;
    }
    const int wave = tid >> 6, lane = tid & 63;
    const int wm = (wave >> 1) * 64, wn = (wave & 1) * 64;
    const int quad = lane >> 4, l16 = lane & 15;
    floatx4 acc[4][4] = {};
    const int cg = (tid & 7) * 4;
    const int rbase = tid >> 3;
    const float* wbase = wgt + (size_t)e * KDIM * NDIM;
    for (int k0 = 0; k0 < KDIM; k0 += 32) {
        __syncthreads();
        #pragma unroll
        for (int p = 0; p < 4; ++p) {
            int row = p * 32 + rbase;
            int t = tok_s[row];
            float4 va = make_float4(0.f, 0.f, 0.f, 0.f);
            if (t >= 0) va = *(const float4*)&inp[(size_t)t * KDIM + k0 + cg];
            As[row * LDW + (cg >> 1)]     = pk2bf(va.x, va.y);
            As[row * LDW + (cg >> 1) + 1] = pk2bf(va.z, va.w);
            float4 vb = *(const float4*)&wbase[(size_t)(out0 + row) * KDIM + k0 + cg];
            Bs[row * LDW + (cg >> 1)]     = pk2bf(vb.x, vb.y);
            Bs[row * LDW + (cg >> 1) + 1] = pk2bf(vb.z, vb.w);
        }
        __syncthreads();
        short8 a[4], b[4];
        #pragma unroll
        for (int i = 0; i < 4; ++i)
            a[i] = *(const short8*)&As[(wm + i * 16 + l16) * LDW + quad * 4];
        #pragma unroll
        for (int i = 0; i < 4; ++i)
            b[i] = *(const short8*)&Bs[(wn + i * 16 + l16) * LDW + quad * 4];
        #pragma unroll
        for (int mi = 0; mi < 4; ++mi)
            #pragma unroll
            for (int ni = 0; ni < 4; ++ni)
                acc[mi][ni] = __builtin_amdgcn_mfma_f32_16x16x32_bf16(
                    a[mi], b[ni], acc[mi][ni], 0, 0, 0);
    }
    #pragma unroll
    for (int mi = 0; mi < 4; ++mi) {
        #pragma unroll
        for (int r = 0; r < 4; ++r) {
            int lrow = wm + mi * 16 + quad * 4 + r;
            int t = tok_s[lrow];
            if (t >= 0) {
                float* orow = out + (size_t)t * NDIM + out0 + wn + l16;
                #pragma unroll
                for (int ni = 0; ni < 4; ++ni)
                    orow[ni * 16] = acc[mi][ni][r];
            }
        }
    }
}

extern "C" void kernel_launch(void* const* d_in, const int* in_sizes, int n_in,
                              void* d_out, int out_size, void* d_ws, size_t ws_size,
                              hipStream_t stream) {
    const float* inp  = (const float*)d_in[0];
    const int*   gate = (const int*)d_in[1];
    const float* wgt  = (const float*)d_in[2];
    float*       out  = (float*)d_out;
    char* w = (char*)d_ws;

    if (ws_size >= WS_REQ) {
        int* tg0  = (int*)(w + O_TG0);
        int* te   = (int*)(w + O_TE);
        int* tend = (int*)(w + O_TEND);
        int* gidx = (int*)(w + O_GIDX);
        int* tok  = (int*)(w + O_TOK);
        ushort_t* pA = (ushort_t*)(w + O_PA);

        map_k<<<1, 1024, 0, stream>>>(gate, gidx, tg0, te, tend);
        gather_k<<<2048, 256, 0, stream>>>(inp, gidx, pA, tok);
        dim3 grid(NDIM / TN, MAXT, 1);
        moe_gemm8_k<<<grid, 256, 0, stream>>>(pA, wgt, tg0, te, tend, tok, out);
    } else {
        int* cnt = (int*)d_ws;
        int* idx = cnt + NE;
        zero_k<<<1, 64, 0, stream>>>(cnt);
        bin_tokens_k<<<BATCH / 256, 256, 0, stream>>>(gate, cnt, idx);
        dim3 grid(NDIM / 128, BATCH / TM, NE);
        moe_gemm_k<<<grid, 256, 0, stream>>>(inp, wgt, cnt, idx, out);
    }
}

// Round 7
// 183.642 us; speedup vs baseline: 1.3744x; 1.3744x over previous
//
#include <hip/hip_runtime.h>
#include <hip/hip_bf16.h>

#define NE    16
#define KDIM  1024
#define NDIM  1024
#define BATCH 8192
#define TM    128
#define TN    128         // round-7: 64->128 (m97 tile shape, 2x MFMA/step)
#define MAXT  96          // max live m-tiles = 64 + 15 = 79, padded

typedef __attribute__((ext_vector_type(8))) short short8;
typedef __attribute__((ext_vector_type(4))) float floatx4;
typedef unsigned short ushort_t;

// ---- ws layout (bytes) ----
#define O_TG0  1024
#define O_TE   2048
#define O_TEND 3072
#define O_GIDX 4096                     // int[8192]
#define O_TOK  36864                    // int[8320]
#define O_PA   73728                    // ushort[(8192+128)*1024]
#define WS_REQ 17113088

#define GLOAD_LDS(gp, lp) __builtin_amdgcn_global_load_lds( \
    (const __attribute__((address_space(1))) unsigned int*)(gp), \
    (__attribute__((address_space(3))) unsigned int*)(lp), 16, 0, 0)

__device__ __forceinline__ unsigned int pk2bf(float x, float y) {
    __hip_bfloat162 h = __float22bfloat162_rn(make_float2(x, y));
    unsigned int u;
    __builtin_memcpy(&u, &h, 4);
    return u;
}

// ---------------- fast path ----------------

// Single-block map: ballot-based ranking (no LDS atomics). Emits gidx
// (token -> sorted slot) + tile map at TM granularity.
__global__ __launch_bounds__(1024) void map_k(
        const int* __restrict__ gate, int* __restrict__ gidx,
        int* __restrict__ tg0, int* __restrict__ te, int* __restrict__ tend) {
    __shared__ int ccnt[128][NE];    // per-chunk per-expert counts (8 KB)
    __shared__ int cbase[128][NE];   // per-chunk exclusive base     (8 KB)
    __shared__ int ebase[NE];
    __shared__ int etot[NE];
    const int tid = threadIdx.x;
    const int wv = tid >> 6, ln = tid & 63;

    ((int*)ccnt)[tid] = 0;
    ((int*)ccnt)[tid + 1024] = 0;
    __syncthreads();

    int e[8], rk[8];
    #pragma unroll
    for (int i = 0; i < 8; ++i) {
        const int chunk = wv * 8 + i;
        const int t = chunk * 64 + ln;
        const int ei = gate[t];
        unsigned long long m = ~0ull;
        #pragma unroll
        for (int b = 0; b < 4; ++b) {
            unsigned long long bb = __ballot(((ei >> b) & 1) != 0);
            m &= ((ei >> b) & 1) ? bb : ~bb;
        }
        const unsigned int lo = (unsigned int)m;
        const unsigned int hi = (unsigned int)(m >> 32);
        const int r = __builtin_amdgcn_mbcnt_hi(
            hi, __builtin_amdgcn_mbcnt_lo(lo, 0));
        if (r == 0) ccnt[chunk][ei] = __popcll(m);
        e[i] = ei; rk[i] = r;
    }
    __syncthreads();

    if (tid < NE) {                   // 16-thread scan over 128 chunks
        int s = 0;
        for (int c = 0; c < 128; ++c) { cbase[c][tid] = s; s += ccnt[c][tid]; }
        etot[tid] = s;
    }
    __syncthreads();

    if (tid == 0) {                   // expert bases + tile map (tiny)
        int o = 0, nt = 0;
        for (int j = 0; j < NE; ++j) {
            ebase[j] = o;
            int c = etot[j];
            for (int rr = 0; rr < c; rr += TM) {
                int r0 = (rr + TM <= c) ? rr : (c > TM ? c - TM : 0);
                tg0[nt] = o + r0; te[nt] = j; tend[nt] = o + c; ++nt;
            }
            o += c;
        }
        for (; nt < MAXT; ++nt) { tg0[nt] = 0; te[nt] = 0; tend[nt] = 0; }
    }
    __syncthreads();

    #pragma unroll
    for (int i = 0; i < 8; ++i) {
        const int chunk = wv * 8 + i;
        const int t = chunk * 64 + ln;
        gidx[t] = ebase[e[i]] + cbase[chunk][e[i]] + rk[i];
    }
}

// token gather: fp32 -> bf16, destination row from gidx (no scans)
__global__ __launch_bounds__(256, 8) void gather_k(
        const float* __restrict__ inp, const int* __restrict__ gidx,
        ushort_t* __restrict__ pA, int* __restrict__ tok) {
    const int b = blockIdx.x, tid = threadIdx.x;
    const int col = (tid & 127) * 8;
    const int half = tid >> 7;
    int g[2]; float4 v0[2], v1[2];
    #pragma unroll
    for (int p = 0; p < 2; ++p) {
        int t = b * 4 + p * 2 + half;
        g[p] = gidx[t];
        v0[p] = *(const float4*)&inp[(size_t)t * KDIM + col];
        v1[p] = *(const float4*)&inp[(size_t)t * KDIM + col + 4];
    }
    #pragma unroll
    for (int p = 0; p < 2; ++p) {
        uint4 u = make_uint4(pk2bf(v0[p].x, v0[p].y), pk2bf(v0[p].z, v0[p].w),
                             pk2bf(v1[p].x, v1[p].y), pk2bf(v1[p].z, v1[p].w));
        *(uint4*)&pA[(size_t)g[p] * KDIM + col] = u;
        if (col == 0) tok[g[p]] = b * 4 + p * 2 + half;
    }
}

// TM=128 x TN=128, BK=64, single-buffer 2-barrier (m97 tile shape):
// A via global_load_lds (bf16 pA), B staged fp32->bf16 through VGPRs,
// XOR-swizzled LDS. 4 waves, each computes 64x64 (acc[4][4], 32 MFMA/step).
// Rationale (r7): guide tile-space at fixed structure: 64^2=343, 128^2=912 TF.
// Our 128x64 = 277 TF sat on that curve; doubling TN doubles MFMA per staged
// A-byte. Grid (8 x 96): col-panel c -> XCD c%8, B slice L2-pinned per XCD.
// NOTE (r1): LDS dbuf regressed (residency).  NOTE (r3): XCD m-swizzle
// regressed.  NOTE (r4): fp32 direct A-gather regressed (FETCH +60MB).
// NOTE (r5): more TLP (64-row tiles, 56% occ) regressed -> not TLP-bound.
// NOTE (r6): reg-staged async split regressed (scratch spill, WRITE +165MB).
__global__ __launch_bounds__(256, 3) void moe_gemm9_k(
        const ushort_t* __restrict__ pA, const float* __restrict__ wgt,
        const int* __restrict__ tg0, const int* __restrict__ teArr,
        const int* __restrict__ tend, const int* __restrict__ tok,
        float* __restrict__ out) {
    const int y   = blockIdx.y;
    const int g0  = tg0[y];
    const int end = tend[y];
    if (g0 >= end) return;
    const int e    = teArr[y];
    const int out0 = blockIdx.x * TN;

    __shared__ ushort_t As[TM][64];   // 16 KB, chunk-swizzled
    __shared__ ushort_t Bs[TN][64];   // 16 KB, chunk-swizzled
    __shared__ int tok_s[TM];

    const int tid = threadIdx.x;
    if (tid < TM) tok_s[tid] = tok[g0 + tid];

    const int wave = tid >> 6, lane = tid & 63;
    const int wm = (wave >> 1) * 64;
    const int wn = (wave & 1) * 64;
    const int quad = lane >> 4, l16 = lane & 15;

    const ushort_t* Ab = pA + (size_t)g0 * KDIM;
    const float*    Bw = wgt + ((size_t)e * NDIM + out0) * KDIM;

    floatx4 acc[4][4] = {};
    const int slotw = wave * 64 + lane;

    for (int k0 = 0; k0 < KDIM; k0 += 64) {
        // B: fp32 global loads first (8 float4 in flight)
        float4 bv[4][2];
        #pragma unroll
        for (int i = 0; i < 4; ++i) {
            int slot = i * 256 + slotw;
            int row = slot >> 3;
            int kc = (slot & 7) ^ (row & 7);
            const float* src = Bw + (size_t)row * KDIM + k0 + kc * 8;
            bv[i][0] = *(const float4*)src;
            bv[i][1] = *(const float4*)(src + 4);
        }
        // A: DMA direct to LDS (issues while B loads are in flight)
        #pragma unroll
        for (int i = 0; i < 4; ++i) {
            int slot = i * 256 + slotw;
            int row = slot >> 3;
            int kc = (slot & 7) ^ (row & 7);
            GLOAD_LDS(Ab + (size_t)row * KDIM + k0 + kc * 8,
                      (ushort_t*)As + (size_t)(i * 256 + wave * 64) * 8);
        }
        // B: cvt + linear ds_write_b128 (conflict-free)
        #pragma unroll
        for (int i = 0; i < 4; ++i) {
            int slot = i * 256 + slotw;
            uint4 u = make_uint4(pk2bf(bv[i][0].x, bv[i][0].y),
                                 pk2bf(bv[i][0].z, bv[i][0].w),
                                 pk2bf(bv[i][1].x, bv[i][1].y),
                                 pk2bf(bv[i][1].z, bv[i][1].w));
            *(uint4*)((ushort_t*)Bs + (size_t)slot * 8) = u;
        }
        __syncthreads();                 // drains A-DMA (vmcnt) + B writes
        #pragma unroll
        for (int s = 0; s < 2; ++s) {
            short8 a[4], b[4];
            #pragma unroll
            for (int i = 0; i < 4; ++i) {
                int r = wm + i * 16 + l16;
                a[i] = *(const short8*)&As[r][((s * 4 + quad) ^ (r & 7)) * 8];
            }
            #pragma unroll
            for (int j = 0; j < 4; ++j) {
                int r = wn + j * 16 + l16;
                b[j] = *(const short8*)&Bs[r][((s * 4 + quad) ^ (r & 7)) * 8];
            }
            #pragma unroll
            for (int mi = 0; mi < 4; ++mi)
                #pragma unroll
                for (int nj = 0; nj < 4; ++nj)
                    acc[mi][nj] = __builtin_amdgcn_mfma_f32_16x16x32_bf16(
                        a[mi], b[nj], acc[mi][nj], 0, 0, 0);
        }
        __syncthreads();                 // protect LDS before next stage
    }

    // C/D layout: col=lane&15, row=quad*4+reg (verified m89/m91)
    #pragma unroll
    for (int mi = 0; mi < 4; ++mi) {
        #pragma unroll
        for (int r = 0; r < 4; ++r) {
            int lrow = wm + mi * 16 + quad * 4 + r;
            if (g0 + lrow < end) {
                int t = tok_s[lrow];
                float* orow = out + (size_t)t * NDIM + out0 + wn + l16;
                #pragma unroll
                for (int nj = 0; nj < 4; ++nj)
                    orow[nj * 16] = acc[mi][nj][r];
            }
        }
    }
}

// ---------------- fallback path (round-1, known-passing) ----------------
#define LDW 20
__global__ void zero_k(int* cnt) {
    if (threadIdx.x < NE) cnt[threadIdx.x] = 0;
}

__global__ void bin_tokens_k(const int* __restrict__ gate, int* cnt, int* idx) {
    int t = blockIdx.x * blockDim.x + threadIdx.x;
    if (t < BATCH) {
        int e = gate[t];
        int p = atomicAdd(&cnt[e], 1);
        idx[e * BATCH + p] = t;
    }
}

__global__ __launch_bounds__(256) void moe_gemm_k(
        const float* __restrict__ inp, const float* __restrict__ wgt,
        const int* __restrict__ cnt, const int* __restrict__ idx,
        float* __restrict__ out) {
    const int e = blockIdx.z;
    const int n_e = cnt[e];
    const int row0 = blockIdx.y * TM;
    if (row0 >= n_e) return;
    const int out0 = blockIdx.x * 128;
    __shared__ unsigned int As[TM * LDW];
    __shared__ unsigned int Bs[TM * LDW];
    __shared__ int tok_s[TM];
    const int tid = threadIdx.x;
    if (tid < TM) {
        int g = row0 + tid;
        tok_s[tid] = (g < n_e) ? idx[e * BATCH + g] : -1;
    }
    const int wave = tid >> 6, lane = tid & 63;
    const int wm = (wave >> 1) * 64, wn = (wave & 1) * 64;
    const int quad = lane >> 4, l16 = lane & 15;
    floatx4 acc[4][4] = {};
    const int cg = (tid & 7) * 4;
    const int rbase = tid >> 3;
    const float* wbase = wgt + (size_t)e * KDIM * NDIM;
    for (int k0 = 0; k0 < KDIM; k0 += 32) {
        __syncthreads();
        #pragma unroll
        for (int p = 0; p < 4; ++p) {
            int row = p * 32 + rbase;
            int t = tok_s[row];
            float4 va = make_float4(0.f, 0.f, 0.f, 0.f);
            if (t >= 0) va = *(const float4*)&inp[(size_t)t * KDIM + k0 + cg];
            As[row * LDW + (cg >> 1)]     = pk2bf(va.x, va.y);
            As[row * LDW + (cg >> 1) + 1] = pk2bf(va.z, va.w);
            float4 vb = *(const float4*)&wbase[(size_t)(out0 + row) * KDIM + k0 + cg];
            Bs[row * LDW + (cg >> 1)]     = pk2bf(vb.x, vb.y);
            Bs[row * LDW + (cg >> 1) + 1] = pk2bf(vb.z, vb.w);
        }
        __syncthreads();
        short8 a[4], b[4];
        #pragma unroll
        for (int i = 0; i < 4; ++i)
            a[i] = *(const short8*)&As[(wm + i * 16 + l16) * LDW + quad * 4];
        #pragma unroll
        for (int i = 0; i < 4; ++i)
            b[i] = *(const short8*)&Bs[(wn + i * 16 + l16) * LDW + quad * 4];
        #pragma unroll
        for (int mi = 0; mi < 4; ++mi)
            #pragma unroll
            for (int ni = 0; ni < 4; ++ni)
                acc[mi][ni] = __builtin_amdgcn_mfma_f32_16x16x32_bf16(
                    a[mi], b[ni], acc[mi][ni], 0, 0, 0);
    }
    #pragma unroll
    for (int mi = 0; mi < 4; ++mi) {
        #pragma unroll
        for (int r = 0; r < 4; ++r) {
            int lrow = wm + mi * 16 + quad * 4 + r;
            int t = tok_s[lrow];
            if (t >= 0) {
                float* orow = out + (size_t)t * NDIM + out0 + wn + l16;
                #pragma unroll
                for (int ni = 0; ni < 4; ++ni)
                    orow[ni * 16] = acc[mi][ni][r];
            }
        }
    }
}

extern "C" void kernel_launch(void* const* d_in, const int* in_sizes, int n_in,
                              void* d_out, int out_size, void* d_ws, size_t ws_size,
                              hipStream_t stream) {
    const float* inp  = (const float*)d_in[0];
    const int*   gate = (const int*)d_in[1];
    const float* wgt  = (const float*)d_in[2];
    float*       out  = (float*)d_out;
    char* w = (char*)d_ws;

    if (ws_size >= WS_REQ) {
        int* tg0  = (int*)(w + O_TG0);
        int* te   = (int*)(w + O_TE);
        int* tend = (int*)(w + O_TEND);
        int* gidx = (int*)(w + O_GIDX);
        int* tok  = (int*)(w + O_TOK);
        ushort_t* pA = (ushort_t*)(w + O_PA);

        map_k<<<1, 1024, 0, stream>>>(gate, gidx, tg0, te, tend);
        gather_k<<<2048, 256, 0, stream>>>(inp, gidx, pA, tok);
        dim3 grid(NDIM / TN, MAXT, 1);
        moe_gemm9_k<<<grid, 256, 0, stream>>>(pA, wgt, tg0, te, tend, tok, out);
    } else {
        int* cnt = (int*)d_ws;
        int* idx = cnt + NE;
        zero_k<<<1, 64, 0, stream>>>(cnt);
        bin_tokens_k<<<BATCH / 256, 256, 0, stream>>>(gate, cnt, idx);
        dim3 grid(NDIM / 128, BATCH / TM, NE);
        moe_gemm_k<<<grid, 256, 0, stream>>>(inp, wgt, cnt, idx, out);
    }
}

// Round 8
// 177.175 us; speedup vs baseline: 1.4246x; 1.0365x over previous
//
#include <hip/hip_runtime.h>
#include <hip/hip_bf16.h>

#define NE    16
#define KDIM  1024
#define NDIM  1024
#define BATCH 8192
#define TM    128
#define TN    64
#define MAXT  96          // max live m-tiles = 64 + 15 = 79, padded

typedef __attribute__((ext_vector_type(8))) short short8;
typedef __attribute__((ext_vector_type(4))) float floatx4;
typedef unsigned short ushort_t;

// ---- ws layout (bytes) ----
#define O_TG0  1024
#define O_TE   2048
#define O_TEND 3072
#define O_GIDX 4096                     // int[8192]
#define O_TOK  36864                    // int[8320]
#define O_PA   73728                    // ushort[(8192+128)*1024]
#define WS_REQ 17113088

#define GLOAD_LDS(gp, lp) __builtin_amdgcn_global_load_lds( \
    (const __attribute__((address_space(1))) unsigned int*)(gp), \
    (__attribute__((address_space(3))) unsigned int*)(lp), 16, 0, 0)

__device__ __forceinline__ unsigned int pk2bf(float x, float y) {
    __hip_bfloat162 h = __float22bfloat162_rn(make_float2(x, y));
    unsigned int u;
    __builtin_memcpy(&u, &h, 4);
    return u;
}

// ---------------- fast path ----------------

// Single-block map: ballot-based ranking (no LDS atomics). Emits gidx
// (token -> sorted slot) + tile map at TM granularity.
__global__ __launch_bounds__(1024) void map_k(
        const int* __restrict__ gate, int* __restrict__ gidx,
        int* __restrict__ tg0, int* __restrict__ te, int* __restrict__ tend) {
    __shared__ int ccnt[128][NE];    // per-chunk per-expert counts (8 KB)
    __shared__ int cbase[128][NE];   // per-chunk exclusive base     (8 KB)
    __shared__ int ebase[NE];
    __shared__ int etot[NE];
    const int tid = threadIdx.x;
    const int wv = tid >> 6, ln = tid & 63;

    ((int*)ccnt)[tid] = 0;
    ((int*)ccnt)[tid + 1024] = 0;
    __syncthreads();

    int e[8], rk[8];
    #pragma unroll
    for (int i = 0; i < 8; ++i) {
        const int chunk = wv * 8 + i;
        const int t = chunk * 64 + ln;
        const int ei = gate[t];
        unsigned long long m = ~0ull;
        #pragma unroll
        for (int b = 0; b < 4; ++b) {
            unsigned long long bb = __ballot(((ei >> b) & 1) != 0);
            m &= ((ei >> b) & 1) ? bb : ~bb;
        }
        const unsigned int lo = (unsigned int)m;
        const unsigned int hi = (unsigned int)(m >> 32);
        const int r = __builtin_amdgcn_mbcnt_hi(
            hi, __builtin_amdgcn_mbcnt_lo(lo, 0));
        if (r == 0) ccnt[chunk][ei] = __popcll(m);
        e[i] = ei; rk[i] = r;
    }
    __syncthreads();

    if (tid < NE) {                   // 16-thread scan over 128 chunks
        int s = 0;
        for (int c = 0; c < 128; ++c) { cbase[c][tid] = s; s += ccnt[c][tid]; }
        etot[tid] = s;
    }
    __syncthreads();

    if (tid == 0) {                   // expert bases + tile map (tiny)
        int o = 0, nt = 0;
        for (int j = 0; j < NE; ++j) {
            ebase[j] = o;
            int c = etot[j];
            for (int rr = 0; rr < c; rr += TM) {
                int r0 = (rr + TM <= c) ? rr : (c > TM ? c - TM : 0);
                tg0[nt] = o + r0; te[nt] = j; tend[nt] = o + c; ++nt;
            }
            o += c;
        }
        for (; nt < MAXT; ++nt) { tg0[nt] = 0; te[nt] = 0; tend[nt] = 0; }
    }
    __syncthreads();

    #pragma unroll
    for (int i = 0; i < 8; ++i) {
        const int chunk = wv * 8 + i;
        const int t = chunk * 64 + ln;
        gidx[t] = ebase[e[i]] + cbase[chunk][e[i]] + rk[i];
    }
}

// token gather: fp32 -> bf16, destination row from gidx (no scans)
__global__ __launch_bounds__(256, 8) void gather_k(
        const float* __restrict__ inp, const int* __restrict__ gidx,
        ushort_t* __restrict__ pA, int* __restrict__ tok) {
    const int b = blockIdx.x, tid = threadIdx.x;
    const int col = (tid & 127) * 8;
    const int half = tid >> 7;
    int g[2]; float4 v0[2], v1[2];
    #pragma unroll
    for (int p = 0; p < 2; ++p) {
        int t = b * 4 + p * 2 + half;
        g[p] = gidx[t];
        v0[p] = *(const float4*)&inp[(size_t)t * KDIM + col];
        v1[p] = *(const float4*)&inp[(size_t)t * KDIM + col + 4];
    }
    #pragma unroll
    for (int p = 0; p < 2; ++p) {
        uint4 u = make_uint4(pk2bf(v0[p].x, v0[p].y), pk2bf(v0[p].z, v0[p].w),
                             pk2bf(v1[p].x, v1[p].y), pk2bf(v1[p].z, v1[p].w));
        *(uint4*)&pA[(size_t)g[p] * KDIM + col] = u;
        if (col == 0) tok[g[p]] = b * 4 + p * 2 + half;
    }
}

// TM=128 x TN=64, BK=128 (round-8: 64->128, halves the k-step count):
// single-buffer 2-barrier template (R2-verified), A via global_load_lds
// (bf16 pA, pre-swizzled source), B staged fp32->bf16 through VGPRs.
// Rationale: duration tracked #steps x stall across R1/R5/R6/R7 (~1900
// cyc/step regardless of occupancy/tile/MFMA-count). BK=128 halves #steps;
// LDS 48.5KB -> 3 blocks/CU == the ~2.8 measured residency of R2, so no
// effective TLP loss (m132's BK=128 regression was at 64KB -> 2 blocks/CU).
// NOTE (r1): LDS dbuf regressed (residency).  NOTE (r3): XCD m-swizzle
// regressed (weights dominate fetch; x-fastest order pins col-panel c to
// XCD c%8).  NOTE (r4): fp32 direct A-gather regressed (FETCH +60MB).
// NOTE (r5): more TLP regressed -> not TLP-bound.  NOTE (r6): reg-staged
// async split regressed (scratch spill).  NOTE (r7): TN=128 regressed
// (2.5 blocks/CU).
__global__ __launch_bounds__(256, 3) void moe_gemm10_k(
        const ushort_t* __restrict__ pA, const float* __restrict__ wgt,
        const int* __restrict__ tg0, const int* __restrict__ teArr,
        const int* __restrict__ tend, const int* __restrict__ tok,
        float* __restrict__ out) {
    const int y   = blockIdx.y;
    const int g0  = tg0[y];
    const int end = tend[y];
    if (g0 >= end) return;
    const int e    = teArr[y];
    const int out0 = blockIdx.x * TN;

    __shared__ ushort_t As[TM][128];  // 32 KB, chunk-swizzled
    __shared__ ushort_t Bs[TN][128];  // 16 KB, chunk-swizzled
    __shared__ int tok_s[TM];

    const int tid = threadIdx.x;
    if (tid < TM) tok_s[tid] = tok[g0 + tid];

    const int wave = tid >> 6, lane = tid & 63;
    const int wm = (wave >> 1) * 64;
    const int wn = (wave & 1) * 32;
    const int quad = lane >> 4, l16 = lane & 15;

    const ushort_t* Ab = pA + (size_t)g0 * KDIM;
    const float*    Bw = wgt + ((size_t)e * NDIM + out0) * KDIM;

    floatx4 acc[4][2] = {};
    const int slotw = wave * 64 + lane;

    for (int k0 = 0; k0 < KDIM; k0 += 128) {
        // B: fp32 global loads first (8 float4 in flight)
        float4 bv[4][2];
        #pragma unroll
        for (int i = 0; i < 4; ++i) {
            int slot = i * 256 + slotw;
            int row = slot >> 4;                    // 16 granules/row
            int kc = (slot & 15) ^ (row & 7);
            const float* src = Bw + (size_t)row * KDIM + k0 + kc * 8;
            bv[i][0] = *(const float4*)src;
            bv[i][1] = *(const float4*)(src + 4);
        }
        // A: DMA direct to LDS, source pre-swizzled (issues while B flies)
        #pragma unroll
        for (int i = 0; i < 8; ++i) {
            int slot = i * 256 + slotw;
            int row = slot >> 4;
            int kc = (slot & 15) ^ (row & 7);
            GLOAD_LDS(Ab + (size_t)row * KDIM + k0 + kc * 8,
                      (ushort_t*)As + (size_t)(i * 256 + wave * 64) * 8);
        }
        // B: cvt + linear ds_write_b128 (conflict-free)
        #pragma unroll
        for (int i = 0; i < 4; ++i) {
            int slot = i * 256 + slotw;
            uint4 u = make_uint4(pk2bf(bv[i][0].x, bv[i][0].y),
                                 pk2bf(bv[i][0].z, bv[i][0].w),
                                 pk2bf(bv[i][1].x, bv[i][1].y),
                                 pk2bf(bv[i][1].z, bv[i][1].w));
            *(uint4*)((ushort_t*)Bs + (size_t)slot * 8) = u;
        }
        __syncthreads();                 // drains A-DMA (vmcnt) + B writes
        #pragma unroll
        for (int s = 0; s < 4; ++s) {    // K=128 -> 4 MFMA sub-steps
            short8 a[4], b[2];
            #pragma unroll
            for (int i = 0; i < 4; ++i) {
                int r = wm + i * 16 + l16;
                a[i] = *(const short8*)&As[r][((s * 4 + quad) ^ (r & 7)) * 8];
            }
            #pragma unroll
            for (int j = 0; j < 2; ++j) {
                int r = wn + j * 16 + l16;
                b[j] = *(const short8*)&Bs[r][((s * 4 + quad) ^ (r & 7)) * 8];
            }
            #pragma unroll
            for (int mi = 0; mi < 4; ++mi)
                #pragma unroll
                for (int nj = 0; nj < 2; ++nj)
                    acc[mi][nj] = __builtin_amdgcn_mfma_f32_16x16x32_bf16(
                        a[mi], b[nj], acc[mi][nj], 0, 0, 0);
        }
        __syncthreads();                 // protect LDS before next stage
    }

    // C/D layout: col=lane&15, row=quad*4+reg (verified m89/m91)
    #pragma unroll
    for (int mi = 0; mi < 4; ++mi) {
        #pragma unroll
        for (int r = 0; r < 4; ++r) {
            int lrow = wm + mi * 16 + quad * 4 + r;
            if (g0 + lrow < end) {
                int t = tok_s[lrow];
                float* orow = out + (size_t)t * NDIM + out0 + wn + l16;
                #pragma unroll
                for (int nj = 0; nj < 2; ++nj)
                    orow[nj * 16] = acc[mi][nj][r];
            }
        }
    }
}

// ---------------- fallback path (round-1, known-passing) ----------------
#define LDW 20
__global__ void zero_k(int* cnt) {
    if (threadIdx.x < NE) cnt[threadIdx.x] = 0;
}

__global__ void bin_tokens_k(const int* __restrict__ gate, int* cnt, int* idx) {
    int t = blockIdx.x * blockDim.x + threadIdx.x;
    if (t < BATCH) {
        int e = gate[t];
        int p = atomicAdd(&cnt[e], 1);
        idx[e * BATCH + p] = t;
    }
}

__global__ __launch_bounds__(256) void moe_gemm_k(
        const float* __restrict__ inp, const float* __restrict__ wgt,
        const int* __restrict__ cnt, const int* __restrict__ idx,
        float* __restrict__ out) {
    const int e = blockIdx.z;
    const int n_e = cnt[e];
    const int row0 = blockIdx.y * TM;
    if (row0 >= n_e) return;
    const int out0 = blockIdx.x * 128;
    __shared__ unsigned int As[TM * LDW];
    __shared__ unsigned int Bs[TM * LDW];
    __shared__ int tok_s[TM];
    const int tid = threadIdx.x;
    if (tid < TM) {
        int g = row0 + tid;
        tok_s[tid] = (g < n_e) ? idx[e * BATCH + g] : -1;
    }
    const int wave = tid >> 6, lane = tid & 63;
    const int wm = (wave >> 1) * 64, wn = (wave & 1) * 64;
    const int quad = lane >> 4, l16 = lane & 15;
    floatx4 acc[4][4] = {};
    const int cg = (tid & 7) * 4;
    const int rbase = tid >> 3;
    const float* wbase = wgt + (size_t)e * KDIM * NDIM;
    for (int k0 = 0; k0 < KDIM; k0 += 32) {
        __syncthreads();
        #pragma unroll
        for (int p = 0; p < 4; ++p) {
            int row = p * 32 + rbase;
            int t = tok_s[row];
            float4 va = make_float4(0.f, 0.f, 0.f, 0.f);
            if (t >= 0) va = *(const float4*)&inp[(size_t)t * KDIM + k0 + cg];
            As[row * LDW + (cg >> 1)]     = pk2bf(va.x, va.y);
            As[row * LDW + (cg >> 1) + 1] = pk2bf(va.z, va.w);
            float4 vb = *(const float4*)&wbase[(size_t)(out0 + row) * KDIM + k0 + cg];
            Bs[row * LDW + (cg >> 1)]     = pk2bf(vb.x, vb.y);
            Bs[row * LDW + (cg >> 1) + 1] = pk2bf(vb.z, vb.w);
        }
        __syncthreads();
        short8 a[4], b[4];
        #pragma unroll
        for (int i = 0; i < 4; ++i)
            a[i] = *(const short8*)&As[(wm + i * 16 + l16) * LDW + quad * 4];
        #pragma unroll
        for (int i = 0; i < 4; ++i)
            b[i] = *(const short8*)&Bs[(wn + i * 16 + l16) * LDW + quad * 4];
        #pragma unroll
        for (int mi = 0; mi < 4; ++mi)
            #pragma unroll
            for (int ni = 0; ni < 4; ++ni)
                acc[mi][ni] = __builtin_amdgcn_mfma_f32_16x16x32_bf16(
                    a[mi], b[ni], acc[mi][ni], 0, 0, 0);
    }
    #pragma unroll
    for (int mi = 0; mi < 4; ++mi) {
        #pragma unroll
        for (int r = 0; r < 4; ++r) {
            int lrow = wm + mi * 16 + quad * 4 + r;
            int t = tok_s[lrow];
            if (t >= 0) {
                float* orow = out + (size_t)t * NDIM + out0 + wn + l16;
                #pragma unroll
                for (int ni = 0; ni < 4; ++ni)
                    orow[ni * 16] = acc[mi][ni][r];
            }
        }
    }
}

extern "C" void kernel_launch(void* const* d_in, const int* in_sizes, int n_in,
                              void* d_out, int out_size, void* d_ws, size_t ws_size,
                              hipStream_t stream) {
    const float* inp  = (const float*)d_in[0];
    const int*   gate = (const int*)d_in[1];
    const float* wgt  = (const float*)d_in[2];
    float*       out  = (float*)d_out;
    char* w = (char*)d_ws;

    if (ws_size >= WS_REQ) {
        int* tg0  = (int*)(w + O_TG0);
        int* te   = (int*)(w + O_TE);
        int* tend = (int*)(w + O_TEND);
        int* gidx = (int*)(w + O_GIDX);
        int* tok  = (int*)(w + O_TOK);
        ushort_t* pA = (ushort_t*)(w + O_PA);

        map_k<<<1, 1024, 0, stream>>>(gate, gidx, tg0, te, tend);
        gather_k<<<2048, 256, 0, stream>>>(inp, gidx, pA, tok);
        dim3 grid(NDIM / TN, MAXT, 1);
        moe_gemm10_k<<<grid, 256, 0, stream>>>(pA, wgt, tg0, te, tend, tok, out);
    } else {
        int* cnt = (int*)d_ws;
        int* idx = cnt + NE;
        zero_k<<<1, 64, 0, stream>>>(cnt);
        bin_tokens_k<<<BATCH / 256, 256, 0, stream>>>(gate, cnt, idx);
        dim3 grid(NDIM / 128, BATCH / TM, NE);
        moe_gemm_k<<<grid, 256, 0, stream>>>(inp, wgt, cnt, idx, out);
    }
}

// Round 9
// 173.993 us; speedup vs baseline: 1.4506x; 1.0183x over previous
//
#include <hip/hip_runtime.h>
#include <hip/hip_bf16.h>

#define NE    16
#define KDIM  1024
#define NDIM  1024
#define BATCH 8192
#define TM    256         // round-9: 128->256, halves logical B traffic
#define TN    64
#define MAXT  48          // sum ceil(c_e/256) <= 16 + 8192/256 = 48

typedef __attribute__((ext_vector_type(8))) short short8;
typedef __attribute__((ext_vector_type(4))) float floatx4;
typedef unsigned short ushort_t;

// ---- ws layout (bytes) ----
#define O_TG0  1024
#define O_TE   2048
#define O_TEND 3072
#define O_TLO  3584                     // int[MAXT] valid-start (tail clamp)
#define O_GIDX 4096                     // int[8192]
#define O_TOK  36864                    // int[8320]
#define O_PA   73728                    // ushort[(8192+128)*1024]
#define WS_REQ 17113088

#define GLOAD_LDS(gp, lp) __builtin_amdgcn_global_load_lds( \
    (const __attribute__((address_space(1))) unsigned int*)(gp), \
    (__attribute__((address_space(3))) unsigned int*)(lp), 16, 0, 0)

__device__ __forceinline__ unsigned int pk2bf(float x, float y) {
    __hip_bfloat162 h = __float22bfloat162_rn(make_float2(x, y));
    unsigned int u;
    __builtin_memcpy(&u, &h, 4);
    return u;
}

// ---------------- fast path ----------------

// Single-block map: ballot-based ranking (no LDS atomics). Emits gidx
// (token -> sorted slot) + tile map at TM=256 granularity with tail clamp.
__global__ __launch_bounds__(1024) void map_k(
        const int* __restrict__ gate, int* __restrict__ gidx,
        int* __restrict__ tg0, int* __restrict__ te, int* __restrict__ tend,
        int* __restrict__ tlo) {
    __shared__ int ccnt[128][NE];    // per-chunk per-expert counts (8 KB)
    __shared__ int cbase[128][NE];   // per-chunk exclusive base     (8 KB)
    __shared__ int ebase[NE];
    __shared__ int etot[NE];
    const int tid = threadIdx.x;
    const int wv = tid >> 6, ln = tid & 63;

    ((int*)ccnt)[tid] = 0;
    ((int*)ccnt)[tid + 1024] = 0;
    __syncthreads();

    int e[8], rk[8];
    #pragma unroll
    for (int i = 0; i < 8; ++i) {
        const int chunk = wv * 8 + i;
        const int t = chunk * 64 + ln;
        const int ei = gate[t];
        unsigned long long m = ~0ull;
        #pragma unroll
        for (int b = 0; b < 4; ++b) {
            unsigned long long bb = __ballot(((ei >> b) & 1) != 0);
            m &= ((ei >> b) & 1) ? bb : ~bb;
        }
        const unsigned int lo = (unsigned int)m;
        const unsigned int hi = (unsigned int)(m >> 32);
        const int r = __builtin_amdgcn_mbcnt_hi(
            hi, __builtin_amdgcn_mbcnt_lo(lo, 0));
        if (r == 0) ccnt[chunk][ei] = __popcll(m);
        e[i] = ei; rk[i] = r;
    }
    __syncthreads();

    if (tid < NE) {                   // 16-thread scan over 128 chunks
        int s = 0;
        for (int c = 0; c < 128; ++c) { cbase[c][tid] = s; s += ccnt[c][tid]; }
        etot[tid] = s;
    }
    __syncthreads();

    if (tid == 0) {                   // expert bases + tile map (tiny)
        int o = 0, nt = 0;
        for (int j = 0; j < NE; ++j) {
            ebase[j] = o;
            int c = etot[j];
            for (int rr = 0; rr < c; rr += TM) {
                int g0;
                if (c >= TM) g0 = o + ((rr + TM <= c) ? rr : c - TM);
                else         g0 = (o <= BATCH - TM) ? o : BATCH - TM;
                tg0[nt] = g0; tlo[nt] = o; te[nt] = j; tend[nt] = o + c; ++nt;
            }
            o += c;
        }
        for (; nt < MAXT; ++nt) { tg0[nt] = 0; te[nt] = 0; tend[nt] = 0; tlo[nt] = 0; }
    }
    __syncthreads();

    #pragma unroll
    for (int i = 0; i < 8; ++i) {
        const int chunk = wv * 8 + i;
        const int t = chunk * 64 + ln;
        gidx[t] = ebase[e[i]] + cbase[chunk][e[i]] + rk[i];
    }
}

// token gather: fp32 -> bf16, destination row from gidx (no scans)
__global__ __launch_bounds__(256, 8) void gather_k(
        const float* __restrict__ inp, const int* __restrict__ gidx,
        ushort_t* __restrict__ pA, int* __restrict__ tok) {
    const int b = blockIdx.x, tid = threadIdx.x;
    const int col = (tid & 127) * 8;
    const int half = tid >> 7;
    int g[2]; float4 v0[2], v1[2];
    #pragma unroll
    for (int p = 0; p < 2; ++p) {
        int t = b * 4 + p * 2 + half;
        g[p] = gidx[t];
        v0[p] = *(const float4*)&inp[(size_t)t * KDIM + col];
        v1[p] = *(const float4*)&inp[(size_t)t * KDIM + col + 4];
    }
    #pragma unroll
    for (int p = 0; p < 2; ++p) {
        uint4 u = make_uint4(pk2bf(v0[p].x, v0[p].y), pk2bf(v0[p].z, v0[p].w),
                             pk2bf(v1[p].x, v1[p].y), pk2bf(v1[p].z, v1[p].w));
        *(uint4*)&pA[(size_t)g[p] * KDIM + col] = u;
        if (col == 0) tok[g[p]] = b * 4 + p * 2 + half;
    }
}

// TM=256 x TN=64, BK=64, single-buffer 2-barrier (R2-verified structure):
// A via global_load_lds (bf16 pA, pre-swizzled source), B staged fp32->bf16
// through VGPRs, XOR-swizzled LDS (8 granules/row — the 0-conflict variant).
// Model (r8): dur ~ total-staged-bytes/CU x f(resident blocks); steps/barriers
// neutral (R2 BK64 == R8 BK128 == 62us). TM=256 halves logical B reads
// (tiles/expert 5->2.5): 647->442 MB staged, while the doubled operand is the
// CHEAP one (A: bf16 DMA from L3-resident pA) — R7 doubled HBM-heavy fp32 B
// and lost residency (33KB, 1.7 blocks); here LDS 41KB keeps 3 resident.
// Tail: c<256 experts get clamped g0 + tlo[] guard (no pA overread).
// NOTE (r1): LDS dbuf regressed.  NOTE (r3): XCD m-swizzle regressed.
// NOTE (r4): fp32 direct A regressed.  NOTE (r5): more TLP regressed.
// NOTE (r6): reg-staged async split regressed (scratch spill).
__global__ __launch_bounds__(256, 3) void moe_gemm11_k(
        const ushort_t* __restrict__ pA, const float* __restrict__ wgt,
        const int* __restrict__ tg0, const int* __restrict__ teArr,
        const int* __restrict__ tend, const int* __restrict__ tloArr,
        const int* __restrict__ tok, float* __restrict__ out) {
    const int y   = blockIdx.y;
    const int g0  = tg0[y];
    const int end = tend[y];
    if (g0 >= end) return;
    const int lo   = tloArr[y];
    const int e    = teArr[y];
    const int out0 = blockIdx.x * TN;

    __shared__ ushort_t As[TM][64];   // 32 KB, chunk-swizzled
    __shared__ ushort_t Bs[TN][64];   //  8 KB, chunk-swizzled
    __shared__ int tok_s[TM];

    const int tid = threadIdx.x;
    tok_s[tid] = tok[g0 + tid];       // 256 threads cover 256 rows

    const int wave = tid >> 6, lane = tid & 63;
    const int wm = wave * 64;         // 4 waves stacked in m; each 64x64
    const int quad = lane >> 4, l16 = lane & 15;

    const ushort_t* Ab = pA + (size_t)g0 * KDIM;
    const float*    Bw = wgt + ((size_t)e * NDIM + out0) * KDIM;

    floatx4 acc[4][4] = {};

    for (int k0 = 0; k0 < KDIM; k0 += 64) {
        // B: fp32 global loads first (4 float4 in flight)
        float4 bv[2][2];
        #pragma unroll
        for (int i = 0; i < 2; ++i) {
            int slot = i * 256 + tid;
            int row = slot >> 3;
            int kc = (slot & 7) ^ (row & 7);
            const float* src = Bw + (size_t)row * KDIM + k0 + kc * 8;
            bv[i][0] = *(const float4*)src;
            bv[i][1] = *(const float4*)(src + 4);
        }
        // A: DMA direct to LDS, source pre-swizzled (8 granule-rounds)
        #pragma unroll
        for (int i = 0; i < 8; ++i) {
            int slot = i * 256 + tid;
            int row = slot >> 3;
            int kc = (slot & 7) ^ (row & 7);
            GLOAD_LDS(Ab + (size_t)row * KDIM + k0 + kc * 8,
                      (ushort_t*)As + (size_t)(i * 256 + wave * 64) * 8);
        }
        // B: cvt + linear ds_write_b128 (conflict-free)
        #pragma unroll
        for (int i = 0; i < 2; ++i) {
            int slot = i * 256 + tid;
            uint4 u = make_uint4(pk2bf(bv[i][0].x, bv[i][0].y),
                                 pk2bf(bv[i][0].z, bv[i][0].w),
                                 pk2bf(bv[i][1].x, bv[i][1].y),
                                 pk2bf(bv[i][1].z, bv[i][1].w));
            *(uint4*)((ushort_t*)Bs + (size_t)slot * 8) = u;
        }
        __syncthreads();                 // drains A-DMA (vmcnt) + B writes
        #pragma unroll
        for (int s = 0; s < 2; ++s) {
            short8 a[4], b[4];
            #pragma unroll
            for (int i = 0; i < 4; ++i) {
                int r = wm + i * 16 + l16;
                a[i] = *(const short8*)&As[r][((s * 4 + quad) ^ (r & 7)) * 8];
            }
            #pragma unroll
            for (int j = 0; j < 4; ++j) {
                int r = j * 16 + l16;
                b[j] = *(const short8*)&Bs[r][((s * 4 + quad) ^ (r & 7)) * 8];
            }
            #pragma unroll
            for (int mi = 0; mi < 4; ++mi)
                #pragma unroll
                for (int nj = 0; nj < 4; ++nj)
                    acc[mi][nj] = __builtin_amdgcn_mfma_f32_16x16x32_bf16(
                        a[mi], b[nj], acc[mi][nj], 0, 0, 0);
        }
        __syncthreads();                 // protect LDS before next stage
    }

    // C/D layout: col=lane&15, row=quad*4+reg (verified m89/m91)
    #pragma unroll
    for (int mi = 0; mi < 4; ++mi) {
        #pragma unroll
        for (int r = 0; r < 4; ++r) {
            int lrow = wm + mi * 16 + quad * 4 + r;
            int gi = g0 + lrow;
            if (gi >= lo && gi < end) {
                int t = tok_s[lrow];
                float* orow = out + (size_t)t * NDIM + out0 + l16;
                #pragma unroll
                for (int nj = 0; nj < 4; ++nj)
                    orow[nj * 16] = acc[mi][nj][r];
            }
        }
    }
}

// ---------------- fallback path (round-1, known-passing) ----------------
#define LDW 20
#define TMF 128
__global__ void zero_k(int* cnt) {
    if (threadIdx.x < NE) cnt[threadIdx.x] = 0;
}

__global__ void bin_tokens_k(const int* __restrict__ gate, int* cnt, int* idx) {
    int t = blockIdx.x * blockDim.x + threadIdx.x;
    if (t < BATCH) {
        int e = gate[t];
        int p = atomicAdd(&cnt[e], 1);
        idx[e * BATCH + p] = t;
    }
}

__global__ __launch_bounds__(256) void moe_gemm_k(
        const float* __restrict__ inp, const float* __restrict__ wgt,
        const int* __restrict__ cnt, const int* __restrict__ idx,
        float* __restrict__ out) {
    const int e = blockIdx.z;
    const int n_e = cnt[e];
    const int row0 = blockIdx.y * TMF;
    if (row0 >= n_e) return;
    const int out0 = blockIdx.x * 128;
    __shared__ unsigned int As[TMF * LDW];
    __shared__ unsigned int Bs[TMF * LDW];
    __shared__ int tok_s[TMF];
    const int tid = threadIdx.x;
    if (tid < TMF) {
        int g = row0 + tid;
        tok_s[tid] = (g < n_e) ? idx[e * BATCH + g] : -1;
    }
    const int wave = tid >> 6, lane = tid & 63;
    const int wm = (wave >> 1) * 64, wn = (wave & 1) * 64;
    const int quad = lane >> 4, l16 = lane & 15;
    floatx4 acc[4][4] = {};
    const int cg = (tid & 7) * 4;
    const int rbase = tid >> 3;
    const float* wbase = wgt + (size_t)e * KDIM * NDIM;
    for (int k0 = 0; k0 < KDIM; k0 += 32) {
        __syncthreads();
        #pragma unroll
        for (int p = 0; p < 4; ++p) {
            int row = p * 32 + rbase;
            int t = tok_s[row];
            float4 va = make_float4(0.f, 0.f, 0.f, 0.f);
            if (t >= 0) va = *(const float4*)&inp[(size_t)t * KDIM + k0 + cg];
            As[row * LDW + (cg >> 1)]     = pk2bf(va.x, va.y);
            As[row * LDW + (cg >> 1) + 1] = pk2bf(va.z, va.w);
            float4 vb = *(const float4*)&wbase[(size_t)(out0 + row) * KDIM + k0 + cg];
            Bs[row * LDW + (cg >> 1)]     = pk2bf(vb.x, vb.y);
            Bs[row * LDW + (cg >> 1) + 1] = pk2bf(vb.z, vb.w);
        }
        __syncthreads();
        short8 a[4], b[4];
        #pragma unroll
        for (int i = 0; i < 4; ++i)
            a[i] = *(const short8*)&As[(wm + i * 16 + l16) * LDW + quad * 4];
        #pragma unroll
        for (int i = 0; i < 4; ++i)
            b[i] = *(const short8*)&Bs[(wn + i * 16 + l16) * LDW + quad * 4];
        #pragma unroll
        for (int mi = 0; mi < 4; ++mi)
            #pragma unroll
            for (int ni = 0; ni < 4; ++ni)
                acc[mi][ni] = __builtin_amdgcn_mfma_f32_16x16x32_bf16(
                    a[mi], b[ni], acc[mi][ni], 0, 0, 0);
    }
    #pragma unroll
    for (int mi = 0; mi < 4; ++mi) {
        #pragma unroll
        for (int r = 0; r < 4; ++r) {
            int lrow = wm + mi * 16 + quad * 4 + r;
            int t = tok_s[lrow];
            if (t >= 0) {
                float* orow = out + (size_t)t * NDIM + out0 + wn + l16;
                #pragma unroll
                for (int ni = 0; ni < 4; ++ni)
                    orow[ni * 16] = acc[mi][ni][r];
            }
        }
    }
}

extern "C" void kernel_launch(void* const* d_in, const int* in_sizes, int n_in,
                              void* d_out, int out_size, void* d_ws, size_t ws_size,
                              hipStream_t stream) {
    const float* inp  = (const float*)d_in[0];
    const int*   gate = (const int*)d_in[1];
    const float* wgt  = (const float*)d_in[2];
    float*       out  = (float*)d_out;
    char* w = (char*)d_ws;

    if (ws_size >= WS_REQ) {
        int* tg0  = (int*)(w + O_TG0);
        int* te   = (int*)(w + O_TE);
        int* tend = (int*)(w + O_TEND);
        int* tlo  = (int*)(w + O_TLO);
        int* gidx = (int*)(w + O_GIDX);
        int* tok  = (int*)(w + O_TOK);
        ushort_t* pA = (ushort_t*)(w + O_PA);

        map_k<<<1, 1024, 0, stream>>>(gate, gidx, tg0, te, tend, tlo);
        gather_k<<<2048, 256, 0, stream>>>(inp, gidx, pA, tok);
        dim3 grid(NDIM / TN, MAXT, 1);
        moe_gemm11_k<<<grid, 256, 0, stream>>>(pA, wgt, tg0, te, tend, tlo,
                                               tok, out);
    } else {
        int* cnt = (int*)d_ws;
        int* idx = cnt + NE;
        zero_k<<<1, 64, 0, stream>>>(cnt);
        bin_tokens_k<<<BATCH / 256, 256, 0, stream>>>(gate, cnt, idx);
        dim3 grid(NDIM / 128, BATCH / TMF, NE);
        moe_gemm_k<<<grid, 256, 0, stream>>>(inp, wgt, cnt, idx, out);
    }
}

// Round 10
// 171.096 us; speedup vs baseline: 1.4752x; 1.0169x over previous
//
#include <hip/hip_runtime.h>
#include <hip/hip_bf16.h>

#define NE    16
#define KDIM  1024
#define NDIM  1024
#define BATCH 8192
#define TM    256
#define TN    64
#define MAXT  48          // sum ceil(c_e/256) <= 47, padded

typedef __attribute__((ext_vector_type(8))) short short8;
typedef __attribute__((ext_vector_type(4))) float floatx4;
typedef unsigned short ushort_t;

// ---- ws layout (bytes) ----
#define O_TG0  1024
#define O_TE   2048
#define O_TEND 3072
#define O_TLO  3584                     // int[MAXT] valid-start (tail clamp)
#define O_GIDX 4096                     // int[8192]
#define O_TOK  36864                    // int[8320]
#define O_PA   73728                    // ushort[(8192+128)*1024]
#define WS_REQ 17113088

#define GLOAD_LDS(gp, lp) __builtin_amdgcn_global_load_lds( \
    (const __attribute__((address_space(1))) unsigned int*)(gp), \
    (__attribute__((address_space(3))) unsigned int*)(lp), 16, 0, 0)

__device__ __forceinline__ unsigned int pk2bf(float x, float y) {
    __hip_bfloat162 h = __float22bfloat162_rn(make_float2(x, y));
    unsigned int u;
    __builtin_memcpy(&u, &h, 4);
    return u;
}

// ---------------- fast path ----------------

// Single-block map: ballot-based ranking (no LDS atomics). Emits gidx
// (token -> sorted slot) + tile map at TM=256 granularity with tail clamp.
__global__ __launch_bounds__(1024) void map_k(
        const int* __restrict__ gate, int* __restrict__ gidx,
        int* __restrict__ tg0, int* __restrict__ te, int* __restrict__ tend,
        int* __restrict__ tlo) {
    __shared__ int ccnt[128][NE];    // per-chunk per-expert counts (8 KB)
    __shared__ int cbase[128][NE];   // per-chunk exclusive base     (8 KB)
    __shared__ int ebase[NE];
    __shared__ int etot[NE];
    const int tid = threadIdx.x;
    const int wv = tid >> 6, ln = tid & 63;

    ((int*)ccnt)[tid] = 0;
    ((int*)ccnt)[tid + 1024] = 0;
    __syncthreads();

    int e[8], rk[8];
    #pragma unroll
    for (int i = 0; i < 8; ++i) {
        const int chunk = wv * 8 + i;
        const int t = chunk * 64 + ln;
        const int ei = gate[t];
        unsigned long long m = ~0ull;
        #pragma unroll
        for (int b = 0; b < 4; ++b) {
            unsigned long long bb = __ballot(((ei >> b) & 1) != 0);
            m &= ((ei >> b) & 1) ? bb : ~bb;
        }
        const unsigned int lo = (unsigned int)m;
        const unsigned int hi = (unsigned int)(m >> 32);
        const int r = __builtin_amdgcn_mbcnt_hi(
            hi, __builtin_amdgcn_mbcnt_lo(lo, 0));
        if (r == 0) ccnt[chunk][ei] = __popcll(m);
        e[i] = ei; rk[i] = r;
    }
    __syncthreads();

    if (tid < NE) {                   // 16-thread scan over 128 chunks
        int s = 0;
        for (int c = 0; c < 128; ++c) { cbase[c][tid] = s; s += ccnt[c][tid]; }
        etot[tid] = s;
    }
    __syncthreads();

    if (tid == 0) {                   // expert bases + tile map (tiny)
        int o = 0, nt = 0;
        for (int j = 0; j < NE; ++j) {
            ebase[j] = o;
            int c = etot[j];
            for (int rr = 0; rr < c; rr += TM) {
                int g0;
                if (c >= TM) g0 = o + ((rr + TM <= c) ? rr : c - TM);
                else         g0 = (o <= BATCH - TM) ? o : BATCH - TM;
                tg0[nt] = g0; tlo[nt] = o; te[nt] = j; tend[nt] = o + c; ++nt;
            }
            o += c;
        }
        for (; nt < MAXT; ++nt) { tg0[nt] = 0; te[nt] = 0; tend[nt] = 0; tlo[nt] = 0; }
    }
    __syncthreads();

    #pragma unroll
    for (int i = 0; i < 8; ++i) {
        const int chunk = wv * 8 + i;
        const int t = chunk * 64 + ln;
        gidx[t] = ebase[e[i]] + cbase[chunk][e[i]] + rk[i];
    }
}

// token gather: fp32 -> bf16, destination row from gidx (no scans)
__global__ __launch_bounds__(256, 8) void gather_k(
        const float* __restrict__ inp, const int* __restrict__ gidx,
        ushort_t* __restrict__ pA, int* __restrict__ tok) {
    const int b = blockIdx.x, tid = threadIdx.x;
    const int col = (tid & 127) * 8;
    const int half = tid >> 7;
    int g[2]; float4 v0[2], v1[2];
    #pragma unroll
    for (int p = 0; p < 2; ++p) {
        int t = b * 4 + p * 2 + half;
        g[p] = gidx[t];
        v0[p] = *(const float4*)&inp[(size_t)t * KDIM + col];
        v1[p] = *(const float4*)&inp[(size_t)t * KDIM + col + 4];
    }
    #pragma unroll
    for (int p = 0; p < 2; ++p) {
        uint4 u = make_uint4(pk2bf(v0[p].x, v0[p].y), pk2bf(v0[p].z, v0[p].w),
                             pk2bf(v1[p].x, v1[p].y), pk2bf(v1[p].z, v1[p].w));
        *(uint4*)&pA[(size_t)g[p] * KDIM + col] = u;
        if (col == 0) tok[g[p]] = b * 4 + p * 2 + half;
    }
}

// TM=256 x TN=64, BK=64 (R9-verified geometry, best so far: 57.5us) +
// round-10 change: B fp32 loads PREFETCHED one k-step ahead in registers,
// surviving a raw end-of-step barrier (no vmcnt drain there). Removes the
// per-step wait-B link of the serial chain:
//   [wait B -> cvt -> ds_write -> sync(drain A-DMA) -> MFMA]   (r2..r9)
//   [cvt(B ready) -> ds_write -> sync -> issue B(k+1) -> MFMA -> rawbar]
// Held state = bv[2][2] only (16 VGPR), static-indexed (r6's spill came from
// holding A+B pointer+data arrays across asm barriers; tripwire: WRITE_SIZE).
// NOTE (r1): LDS dbuf regressed. (r3): XCD m-swizzle regressed. (r4): fp32
// direct A regressed. (r5): more TLP regressed. (r6): reg async-split spilled.
// (r7): TN=128 regressed. (r8): BK=128 neutral. (r9): TM=256 -4.5us.
__global__ __launch_bounds__(256, 3) void moe_gemm12_k(
        const ushort_t* __restrict__ pA, const float* __restrict__ wgt,
        const int* __restrict__ tg0, const int* __restrict__ teArr,
        const int* __restrict__ tend, const int* __restrict__ tloArr,
        const int* __restrict__ tok, float* __restrict__ out) {
    const int y   = blockIdx.y;
    const int g0  = tg0[y];
    const int end = tend[y];
    if (g0 >= end) return;
    const int lo   = tloArr[y];
    const int e    = teArr[y];
    const int out0 = blockIdx.x * TN;

    __shared__ ushort_t As[TM][64];   // 32 KB, chunk-swizzled
    __shared__ ushort_t Bs[TN][64];   //  8 KB, chunk-swizzled
    __shared__ int tok_s[TM];

    const int tid = threadIdx.x;
    tok_s[tid] = tok[g0 + tid];       // 256 threads cover 256 rows

    const int wave = tid >> 6, lane = tid & 63;
    const int wm = wave * 64;         // 4 waves stacked in m; each 64x64
    const int quad = lane >> 4, l16 = lane & 15;

    const ushort_t* Ab = pA + (size_t)g0 * KDIM;
    const float*    Bw = wgt + ((size_t)e * NDIM + out0) * KDIM;

    // B source addresses (swizzled granule), per thread: 2 rows
    const int brow0 = tid >> 3;              // 0..31
    const int brow1 = brow0 + 32;
    const int bkc0  = ((tid & 7) ^ (brow0 & 7)) * 8;
    const int bkc1  = ((tid & 7) ^ (brow1 & 7)) * 8;
    const float* bsrc0 = Bw + (size_t)brow0 * KDIM + bkc0;
    const float* bsrc1 = Bw + (size_t)brow1 * KDIM + bkc1;

    floatx4 acc[4][4] = {};
    float4 bv00, bv01, bv10, bv11;    // held B prefetch (16 VGPR, no arrays)

    // prologue: B(k0=0) loads
    bv00 = *(const float4*)(bsrc0);
    bv01 = *(const float4*)(bsrc0 + 4);
    bv10 = *(const float4*)(bsrc1);
    bv11 = *(const float4*)(bsrc1 + 4);

    for (int k0 = 0; k0 < KDIM; k0 += 64) {
        // A: DMA direct to LDS, source pre-swizzled (8 granule-rounds)
        #pragma unroll
        for (int i = 0; i < 8; ++i) {
            int slot = i * 256 + tid;
            int row = slot >> 3;
            int kc = (slot & 7) ^ (row & 7);
            GLOAD_LDS(Ab + (size_t)row * KDIM + k0 + kc * 8,
                      (ushort_t*)As + (size_t)(i * 256 + wave * 64) * 8);
        }
        // B: cvt + linear ds_write_b128 (loads issued LAST step — wait ~hidden)
        {
            uint4 u0 = make_uint4(pk2bf(bv00.x, bv00.y), pk2bf(bv00.z, bv00.w),
                                  pk2bf(bv01.x, bv01.y), pk2bf(bv01.z, bv01.w));
            *(uint4*)((ushort_t*)Bs + (size_t)tid * 8) = u0;
            uint4 u1 = make_uint4(pk2bf(bv10.x, bv10.y), pk2bf(bv10.z, bv10.w),
                                  pk2bf(bv11.x, bv11.y), pk2bf(bv11.z, bv11.w));
            *(uint4*)((ushort_t*)Bs + (size_t)(256 + tid) * 8) = u1;
        }
        __syncthreads();                 // drains A-DMA (vmcnt) + B writes

        // issue NEXT step's B loads; they fly through MFMA + raw barrier
        if (k0 + 64 < KDIM) {
            bv00 = *(const float4*)(bsrc0 + k0 + 64);
            bv01 = *(const float4*)(bsrc0 + k0 + 68);
            bv10 = *(const float4*)(bsrc1 + k0 + 64);
            bv11 = *(const float4*)(bsrc1 + k0 + 68);
        }

        #pragma unroll
        for (int s = 0; s < 2; ++s) {
            short8 a[4], b[4];
            #pragma unroll
            for (int i = 0; i < 4; ++i) {
                int r = wm + i * 16 + l16;
                a[i] = *(const short8*)&As[r][((s * 4 + quad) ^ (r & 7)) * 8];
            }
            #pragma unroll
            for (int j = 0; j < 4; ++j) {
                int r = j * 16 + l16;
                b[j] = *(const short8*)&Bs[r][((s * 4 + quad) ^ (r & 7)) * 8];
            }
            #pragma unroll
            for (int mi = 0; mi < 4; ++mi)
                #pragma unroll
                for (int nj = 0; nj < 4; ++nj)
                    acc[mi][nj] = __builtin_amdgcn_mfma_f32_16x16x32_bf16(
                        a[mi], b[nj], acc[mi][nj], 0, 0, 0);
        }
        // end-of-step barrier WITHOUT vmcnt drain (B prefetch stays in flight)
        asm volatile("s_waitcnt lgkmcnt(0)" ::: "memory");
        __builtin_amdgcn_sched_barrier(0);
        __builtin_amdgcn_s_barrier();
    }

    // C/D layout: col=lane&15, row=quad*4+reg (verified m89/m91)
    #pragma unroll
    for (int mi = 0; mi < 4; ++mi) {
        #pragma unroll
        for (int r = 0; r < 4; ++r) {
            int lrow = wm + mi * 16 + quad * 4 + r;
            int gi = g0 + lrow;
            if (gi >= lo && gi < end) {
                int t = tok_s[lrow];
                float* orow = out + (size_t)t * NDIM + out0 + l16;
                #pragma unroll
                for (int nj = 0; nj < 4; ++nj)
                    orow[nj * 16] = acc[mi][nj][r];
            }
        }
    }
}

// ---------------- fallback path (round-1, known-passing) ----------------
#define LDW 20
#define TMF 128
__global__ void zero_k(int* cnt) {
    if (threadIdx.x < NE) cnt[threadIdx.x] = 0;
}

__global__ void bin_tokens_k(const int* __restrict__ gate, int* cnt, int* idx) {
    int t = blockIdx.x * blockDim.x + threadIdx.x;
    if (t < BATCH) {
        int e = gate[t];
        int p = atomicAdd(&cnt[e], 1);
        idx[e * BATCH + p] = t;
    }
}

__global__ __launch_bounds__(256) void moe_gemm_k(
        const float* __restrict__ inp, const float* __restrict__ wgt,
        const int* __restrict__ cnt, const int* __restrict__ idx,
        float* __restrict__ out) {
    const int e = blockIdx.z;
    const int n_e = cnt[e];
    const int row0 = blockIdx.y * TMF;
    if (row0 >= n_e) return;
    const int out0 = blockIdx.x * 128;
    __shared__ unsigned int As[TMF * LDW];
    __shared__ unsigned int Bs[TMF * LDW];
    __shared__ int tok_s[TMF];
    const int tid = threadIdx.x;
    if (tid < TMF) {
        int g = row0 + tid;
        tok_s[tid] = (g < n_e) ? idx[e * BATCH + g] : -1;
    }
    const int wave = tid >> 6, lane = tid & 63;
    const int wm = (wave >> 1) * 64, wn = (wave & 1) * 64;
    const int quad = lane >> 4, l16 = lane & 15;
    floatx4 acc[4][4] = {};
    const int cg = (tid & 7) * 4;
    const int rbase = tid >> 3;
    const float* wbase = wgt + (size_t)e * KDIM * NDIM;
    for (int k0 = 0; k0 < KDIM; k0 += 32) {
        __syncthreads();
        #pragma unroll
        for (int p = 0; p < 4; ++p) {
            int row = p * 32 + rbase;
            int t = tok_s[row];
            float4 va = make_float4(0.f, 0.f, 0.f, 0.f);
            if (t >= 0) va = *(const float4*)&inp[(size_t)t * KDIM + k0 + cg];
            As[row * LDW + (cg >> 1)]     = pk2bf(va.x, va.y);
            As[row * LDW + (cg >> 1) + 1] = pk2bf(va.z, va.w);
            float4 vb = *(const float4*)&wbase[(size_t)(out0 + row) * KDIM + k0 + cg];
            Bs[row * LDW + (cg >> 1)]     = pk2bf(vb.x, vb.y);
            Bs[row * LDW + (cg >> 1) + 1] = pk2bf(vb.z, vb.w);
        }
        __syncthreads();
        short8 a[4], b[4];
        #pragma unroll
        for (int i = 0; i < 4; ++i)
            a[i] = *(const short8*)&As[(wm + i * 16 + l16) * LDW + quad * 4];
        #pragma unroll
        for (int i = 0; i < 4; ++i)
            b[i] = *(const short8*)&Bs[(wn + i * 16 + l16) * LDW + quad * 4];
        #pragma unroll
        for (int mi = 0; mi < 4; ++mi)
            #pragma unroll
            for (int ni = 0; ni < 4; ++ni)
                acc[mi][ni] = __builtin_amdgcn_mfma_f32_16x16x32_bf16(
                    a[mi], b[ni], acc[mi][ni], 0, 0, 0);
    }
    #pragma unroll
    for (int mi = 0; mi < 4; ++mi) {
        #pragma unroll
        for (int r = 0; r < 4; ++r) {
            int lrow = wm + mi * 16 + quad * 4 + r;
            int t = tok_s[lrow];
            if (t >= 0) {
                float* orow = out + (size_t)t * NDIM + out0 + wn + l16;
                #pragma unroll
                for (int ni = 0; ni < 4; ++ni)
                    orow[ni * 16] = acc[mi][ni][r];
            }
        }
    }
}

extern "C" void kernel_launch(void* const* d_in, const int* in_sizes, int n_in,
                              void* d_out, int out_size, void* d_ws, size_t ws_size,
                              hipStream_t stream) {
    const float* inp  = (const float*)d_in[0];
    const int*   gate = (const int*)d_in[1];
    const float* wgt  = (const float*)d_in[2];
    float*       out  = (float*)d_out;
    char* w = (char*)d_ws;

    if (ws_size >= WS_REQ) {
        int* tg0  = (int*)(w + O_TG0);
        int* te   = (int*)(w + O_TE);
        int* tend = (int*)(w + O_TEND);
        int* tlo  = (int*)(w + O_TLO);
        int* gidx = (int*)(w + O_GIDX);
        int* tok  = (int*)(w + O_TOK);
        ushort_t* pA = (ushort_t*)(w + O_PA);

        map_k<<<1, 1024, 0, stream>>>(gate, gidx, tg0, te, tend, tlo);
        gather_k<<<2048, 256, 0, stream>>>(inp, gidx, pA, tok);
        dim3 grid(NDIM / TN, MAXT, 1);
        moe_gemm12_k<<<grid, 256, 0, stream>>>(pA, wgt, tg0, te, tend, tlo,
                                               tok, out);
    } else {
        int* cnt = (int*)d_ws;
        int* idx = cnt + NE;
        zero_k<<<1, 64, 0, stream>>>(cnt);
        bin_tokens_k<<<BATCH / 256, 256, 0, stream>>>(gate, cnt, idx);
        dim3 grid(NDIM / 128, BATCH / TMF, NE);
        moe_gemm_k<<<grid, 256, 0, stream>>>(inp, wgt, cnt, idx, out);
    }
}